// Round 1
// baseline (28.858 us; speedup 1.0000x reference)
//
#include <hip/hip_runtime.h>

// SingleCurveDeformLayer: 2-step Euler RBF flow.
//   land = [src(2048) ; tgt(2048)] per batch, mom nonzero only on src rows.
//   step1: shape1_i = land_i + 0.5 * sum_{j<2048} exp(-|land_i - src_j|^2/s2) * mom_j   (all 4096 i)
//   step2: out_i    = shape1_i + 0.5 * sum_{j<2048} exp(-|shape1_i - shape1_j|^2/s2) * mom_j  (target i only)
// Workspace holds shape1 [B][4096][2] fp32.

constexpr int N      = 2048;   // n_src == n_tgt
constexpr int TPB    = 256;
constexpr int SPLIT  = 8;              // lanes cooperating per output point
constexpr int PTS    = TPB / SPLIT;    // 32 points per block
constexpr float TAU  = 0.5f;           // 1/(N_T-1), N_T=3

template<int STEP>
__global__ __launch_bounds__(TPB)
void deform_kernel(const float* __restrict__ momentum,
                   const float* __restrict__ source_init,
                   const float* __restrict__ target_init,
                   const float* __restrict__ sigmaV2,
                   float* __restrict__ shape1,   // ws: [B][2N][2]
                   float* __restrict__ out)      // [B][N][2]
{
    __shared__ float4 sj[N];   // (x, y, mx, my) per source point: 32 KB

    const int tid  = threadIdx.x;
    const int ppb  = (STEP == 1) ? 2 * N : N;         // points per batch this step
    const int bpb  = ppb / PTS;                       // blocks per batch
    const int b    = blockIdx.x / bpb;
    const int pblk = blockIdx.x % bpb;

    // ---- stage source j-data into LDS (coalesced float2 loads) ----
    for (int k = tid; k < N; k += TPB) {
        float px, py;
        if (STEP == 1) {
            px = source_init[(b * N + k) * 2 + 0];
            py = source_init[(b * N + k) * 2 + 1];
        } else {
            px = shape1[(b * 2 * N + k) * 2 + 0];
            py = shape1[(b * 2 * N + k) * 2 + 1];
        }
        const float mx = momentum[(b * N + k) * 2 + 0];
        const float my = momentum[(b * N + k) * 2 + 1];
        sj[k] = make_float4(px, py, mx, my);
    }
    __syncthreads();

    const int c  = tid & (SPLIT - 1);       // chunk lane
    const int pi = pblk * PTS + (tid >> 3); // point index within batch

    // ---- my i-position ----
    float xi, yi;
    if (STEP == 1) {
        if (pi < N) {
            xi = source_init[(b * N + pi) * 2 + 0];
            yi = source_init[(b * N + pi) * 2 + 1];
        } else {
            xi = target_init[(b * N + (pi - N)) * 2 + 0];
            yi = target_init[(b * N + (pi - N)) * 2 + 1];
        }
    } else {
        xi = shape1[(b * 2 * N + N + pi) * 2 + 0];
        yi = shape1[(b * 2 * N + N + pi) * 2 + 1];
    }

    const float ninv = -1.0f / sigmaV2[0];

    // ---- pair loop: j = t*SPLIT + c (consecutive float4 across the 8 chunks
    //      of a wave -> 128B span, bank-conflict-free; same-c lanes broadcast) ----
    float ax = 0.0f, ay = 0.0f;
    #pragma unroll 4
    for (int t = 0; t < N / SPLIT; ++t) {
        const float4 s = sj[t * SPLIT + c];
        const float dx = xi - s.x;
        const float dy = yi - s.y;
        const float w  = __expf((dx * dx + dy * dy) * ninv);
        ax = fmaf(w, s.z, ax);
        ay = fmaf(w, s.w, ay);
    }

    // ---- reduce across the 8 cooperating lanes (adjacent in the wave) ----
    ax += __shfl_xor(ax, 1); ay += __shfl_xor(ay, 1);
    ax += __shfl_xor(ax, 2); ay += __shfl_xor(ay, 2);
    ax += __shfl_xor(ax, 4); ay += __shfl_xor(ay, 4);

    if (c == 0) {
        const float ox = xi + TAU * ax;
        const float oy = yi + TAU * ay;
        if (STEP == 1) {
            shape1[(b * 2 * N + pi) * 2 + 0] = ox;
            shape1[(b * 2 * N + pi) * 2 + 1] = oy;
        } else {
            out[(b * N + pi) * 2 + 0] = ox;
            out[(b * N + pi) * 2 + 1] = oy;
        }
    }
}

extern "C" void kernel_launch(void* const* d_in, const int* in_sizes, int n_in,
                              void* d_out, int out_size, void* d_ws, size_t ws_size,
                              hipStream_t stream)
{
    const float* momentum    = (const float*)d_in[0];
    const float* source_init = (const float*)d_in[1];
    const float* target_init = (const float*)d_in[2];
    const float* sigmaV2     = (const float*)d_in[3];
    float* out    = (float*)d_out;
    float* shape1 = (float*)d_ws;   // B * 4096 * 2 floats = 128 KB

    const int B = in_sizes[0] / (N * 2);   // 4

    dim3 blk(TPB);
    // step 1: all 2N landmarks per batch
    deform_kernel<1><<<dim3(B * (2 * N / PTS)), blk, 0, stream>>>(
        momentum, source_init, target_init, sigmaV2, shape1, out);
    // step 2: target half only
    deform_kernel<2><<<dim3(B * (N / PTS)), blk, 0, stream>>>(
        momentum, source_init, target_init, sigmaV2, shape1, out);
}

// Round 2
// 24.760 us; speedup vs baseline: 1.1655x; 1.1655x over previous
//
#include <hip/hip_runtime.h>

// SingleCurveDeformLayer: 2-step Euler RBF flow.
//   land = [src(2048) ; tgt(2048)] per batch, mom nonzero only on src rows.
//   step1: shape1_i = land_i + TAU * sum_{j<N} exp(-|land_i - src_j|^2/s2) * mom_j   (all 2N i)
//   step2: out_i    = shape1_i + TAU * sum_{j<N} exp(-|shape1_i - shape1_j|^2/s2) * mom_j  (tgt i)
// Workspace holds shape1 [B][2N][2] fp32.
//
// Decomposition: lane owns MP=4 i-points and 1/SPLIT of the j-range.
//   wave = 2 p-groups x 32 j-chunks; per iteration 32 consecutive float4 LDS
//   reads (512B, conflict-free, broadcast across the two halves); each
//   ds_read_b128 serves 64 lanes x 4 points = 256 pairs (4x fewer LDS instrs
//   than the R1 kernel, which was LDS-throughput-bound at ~15us).

constexpr int N     = 2048;             // n_src == n_tgt
constexpr int TPB   = 256;              // 4 waves
constexpr int SPLIT = 32;               // j-chunks (lanes) per point-group
constexpr int MP    = 4;                // i-points per lane
constexpr int PPW   = (64 / SPLIT) * MP;   // points per wave = 8
constexpr int PPB   = PPW * (TPB / 64);    // points per block = 32
constexpr int NJ    = N / SPLIT;           // j-iterations per lane = 64
constexpr float TAU = 0.5f;                // 1/(N_T-1), N_T=3

template<int STEP>
__global__ __launch_bounds__(TPB)
void deform_kernel(const float* __restrict__ momentum,
                   const float* __restrict__ source_init,
                   const float* __restrict__ target_init,
                   const float* __restrict__ sigmaV2,
                   float* __restrict__ shape1,   // ws: [B][2N][2]
                   float* __restrict__ out)      // [B][N][2]
{
    __shared__ float4 sj[N];   // (x, y, TAU*mx, TAU*my) per source point: 32 KB

    const int tid  = threadIdx.x;
    const int ppb  = (STEP == 1) ? 2 * N : N;   // points per batch this step
    const int bpb  = ppb / PPB;                 // blocks per batch
    const int b    = blockIdx.x / bpb;
    const int pblk = blockIdx.x % bpb;

    // ---- stage source j-data into LDS ----
    for (int k = tid; k < N; k += TPB) {
        float px, py;
        if (STEP == 1) {
            px = source_init[(b * N + k) * 2 + 0];
            py = source_init[(b * N + k) * 2 + 1];
        } else {
            px = shape1[(b * 2 * N + k) * 2 + 0];
            py = shape1[(b * 2 * N + k) * 2 + 1];
        }
        const float mx = momentum[(b * N + k) * 2 + 0];
        const float my = momentum[(b * N + k) * 2 + 1];
        sj[k] = make_float4(px, py, mx * TAU, my * TAU);
    }
    __syncthreads();

    const int wave = tid >> 6;
    const int lane = tid & 63;
    const int c    = lane & (SPLIT - 1);   // j-chunk
    const int p    = lane >> 5;            // point-group within wave (0..1)
    // this lane's 4 point indices (within batch): pi0 + m, m = 0..3
    const int pi0  = pblk * PPB + wave * PPW + p * MP;

    // ---- my i-positions ----
    float xi[MP], yi[MP];
    #pragma unroll
    for (int m = 0; m < MP; ++m) {
        const int pi = pi0 + m;
        if (STEP == 1) {
            if (pi < N) {
                xi[m] = source_init[(b * N + pi) * 2 + 0];
                yi[m] = source_init[(b * N + pi) * 2 + 1];
            } else {
                xi[m] = target_init[(b * N + pi - N) * 2 + 0];
                yi[m] = target_init[(b * N + pi - N) * 2 + 1];
            }
        } else {
            xi[m] = shape1[(b * 2 * N + N + pi) * 2 + 0];
            yi[m] = shape1[(b * 2 * N + N + pi) * 2 + 1];
        }
    }

    const float ninv = -1.0f / sigmaV2[0];

    float ax[MP] = {0.f, 0.f, 0.f, 0.f};
    float ay[MP] = {0.f, 0.f, 0.f, 0.f};

    // ---- pair loop: j = t*SPLIT + c ----
    #pragma unroll 4
    for (int t = 0; t < NJ; ++t) {
        const float4 s = sj[t * SPLIT + c];
        #pragma unroll
        for (int m = 0; m < MP; ++m) {
            const float dx = xi[m] - s.x;
            const float dy = yi[m] - s.y;
            const float w  = __expf(fmaf(dy, dy, dx * dx) * ninv);
            ax[m] = fmaf(w, s.z, ax[m]);
            ay[m] = fmaf(w, s.w, ay[m]);
        }
    }

    // ---- reduce across the 32 j-chunk lanes of this point-group ----
    #pragma unroll
    for (int m = 0; m < MP; ++m) {
        ax[m] += __shfl_xor(ax[m], 1);  ay[m] += __shfl_xor(ay[m], 1);
        ax[m] += __shfl_xor(ax[m], 2);  ay[m] += __shfl_xor(ay[m], 2);
        ax[m] += __shfl_xor(ax[m], 4);  ay[m] += __shfl_xor(ay[m], 4);
        ax[m] += __shfl_xor(ax[m], 8);  ay[m] += __shfl_xor(ay[m], 8);
        ax[m] += __shfl_xor(ax[m], 16); ay[m] += __shfl_xor(ay[m], 16);
    }

    if (c == 0) {
        #pragma unroll
        for (int m = 0; m < MP; ++m) {
            const int pi = pi0 + m;
            const float ox = xi[m] + ax[m];   // TAU already folded into mom
            const float oy = yi[m] + ay[m];
            if (STEP == 1) {
                shape1[(b * 2 * N + pi) * 2 + 0] = ox;
                shape1[(b * 2 * N + pi) * 2 + 1] = oy;
            } else {
                out[(b * N + pi) * 2 + 0] = ox;
                out[(b * N + pi) * 2 + 1] = oy;
            }
        }
    }
}

extern "C" void kernel_launch(void* const* d_in, const int* in_sizes, int n_in,
                              void* d_out, int out_size, void* d_ws, size_t ws_size,
                              hipStream_t stream)
{
    const float* momentum    = (const float*)d_in[0];
    const float* source_init = (const float*)d_in[1];
    const float* target_init = (const float*)d_in[2];
    const float* sigmaV2     = (const float*)d_in[3];
    float* out    = (float*)d_out;
    float* shape1 = (float*)d_ws;   // B * 4096 * 2 floats = 128 KB

    const int B = in_sizes[0] / (N * 2);   // 4

    dim3 blk(TPB);
    // step 1: all 2N landmarks per batch  -> B * 4096/32 = 512 blocks
    deform_kernel<1><<<dim3(B * (2 * N / PPB)), blk, 0, stream>>>(
        momentum, source_init, target_init, sigmaV2, shape1, out);
    // step 2: target half only            -> B * 2048/32 = 256 blocks
    deform_kernel<2><<<dim3(B * (N / PPB)), blk, 0, stream>>>(
        momentum, source_init, target_init, sigmaV2, shape1, out);
}